// Round 9
// baseline (517.791 us; speedup 1.0000x reference)
//
#include <hip/hip_runtime.h>
#include <stdint.h>

#define SEQ    4096
#define HID    2048
#define NQKV   6144
#define QKW    4096   // width of the QK row-major buffer (Q | K)
#define NH     16
#define HD     128
#define SCALE  0.08838834764831845f
#define SC2    0.1275174400460405f   // SCALE * log2(e): softmax in exp2 domain
#define THR2   11.5f                 // defer-max threshold (~e^8 in log2 units)
#define GQC    32     // split-KV chunks for global-query path (128 kv each)

typedef unsigned short u16;
typedef __attribute__((ext_vector_type(8))) short bf16x8;
typedef __attribute__((ext_vector_type(4))) float f32x4;

__device__ __forceinline__ u16 f2bf(float f) {
  union { float f; unsigned u; } v; v.f = f;
  unsigned r = v.u + 0x7FFFu + ((v.u >> 16) & 1u);
  return (u16)(r >> 16);
}

__device__ __forceinline__ float bf2f(u16 b) {
  union { unsigned u; float f; } c; c.u = ((unsigned)b) << 16; return c.f;
}

__device__ __forceinline__ void async16(const u16* g, u16* l) {
  __builtin_amdgcn_global_load_lds(
      (const __attribute__((address_space(1))) unsigned int*)g,
      (__attribute__((address_space(3))) unsigned int*)l, 16, 0, 0);
}

// ---------------- prep: X->bf16 convert + 4 weight transposes + counter zero ----------------
__global__ __launch_bounds__(256) void prep(const float* __restrict__ X,
                                            const float* __restrict__ W0,
                                            const float* __restrict__ W1,
                                            const float* __restrict__ W2,
                                            const float* __restrict__ W3,
                                            u16* __restrict__ Xbf,
                                            u16* __restrict__ Wcat,
                                            u16* __restrict__ Wot,
                                            unsigned* __restrict__ cnt) {
  const int bx = blockIdx.x;
  const int t = threadIdx.x;
  if (bx == 0 && t < NH) cnt[t] = 0u;     // zero split-K completion counters
  if (bx < 8192) {
    int i = bx * 256 + t;
    float4 v = ((const float4*)X)[i];
    ushort4 o;
    o.x = f2bf(v.x); o.y = f2bf(v.y); o.z = f2bf(v.z); o.w = f2bf(v.w);
    ((ushort4*)Xbf)[i] = o;
    return;
  }
  __shared__ __align__(16) u16 Ts[64 * 68];
  const int b = bx - 8192;
  const int z = b >> 10;
  const int k0 = ((b >> 5) & 31) * 64;
  const int n0 = (b & 31) * 64;
  const float* W = (z == 0) ? W0 : (z == 1) ? W1 : (z == 2) ? W2 : W3;
  u16* Wt = (z < 3) ? (Wcat + (size_t)z * 2048 * 2048) : Wot;
#pragma unroll
  for (int p = 0; p < 4; ++p) {
    int f = (t + p * 256) * 4;
    int r = f >> 6, c = f & 63;            // r=k_local, c=n_local
    float4 v = *(const float4*)&W[(size_t)(k0 + r) * 2048 + n0 + c];
    ushort4 o; o.x = f2bf(v.x); o.y = f2bf(v.y); o.z = f2bf(v.z); o.w = f2bf(v.w);
    *(ushort4*)&Ts[r * 68 + c] = o;
  }
  __syncthreads();
#pragma unroll
  for (int p = 0; p < 4; ++p) {
    int g = (t + p * 256) * 4;
    int r = g >> 6, c = g & 63;            // r=n_local, c=k_local
    ushort4 o;
    o.x = Ts[(c + 0) * 68 + r];
    o.y = Ts[(c + 1) * 68 + r];
    o.z = Ts[(c + 2) * 68 + r];
    o.w = Ts[(c + 3) * 68 + r];
    *(ushort4*)&Wt[(size_t)(n0 + r) * 2048 + k0 + c] = o;
  }
}

// ---------------- 128x128 GEMM, m97 structure + LDS slot-swizzle (frozen) ----------------
// R5 verified: swizzle -> SQ_LDS_BANK_CONFLICT 1.26e7 -> 0; at the m97
// structural ceiling (MfmaUtil 37%, 15% HBM); 8-phase escape nulled 3x.
template <typename OutT, bool WVT>
__global__ __launch_bounds__(256) void gemm_bt(const u16* __restrict__ A,
                                               const u16* __restrict__ B,
                                               OutT* __restrict__ C,
                                               u16* __restrict__ VTout,
                                               int K, int ldc) {
  __shared__ __align__(16) u16 As0[128 * 32];
  __shared__ __align__(16) u16 As1[128 * 32];
  __shared__ __align__(16) u16 Bs0[128 * 32];
  __shared__ __align__(16) u16 Bs1[128 * 32];
  const int m0 = blockIdx.y * 128;
  const int n0 = blockIdx.x * 128;
  const int tid = threadIdx.x;
  const int wid = tid >> 6;
  const int lane = tid & 63;
  const int wm = wid & 1, wn = wid >> 1;
  const int l15 = lane & 15, g4 = lane >> 4;

  const int srow = wid * 32 + (lane >> 2);
  const int scol = ((lane & 3) ^ ((lane >> 3) & 3)) * 8;
  const int fsw = (l15 >> 1) & 3;

  f32x4 acc[4][4] = {};

  const u16* pa0 = &A[(size_t)(m0 + srow) * K + scol];
  const u16* pa1 = &A[(size_t)(m0 + srow + 16) * K + scol];
  const u16* pb0 = &B[(size_t)(n0 + srow) * K + scol];
  const u16* pb1 = &B[(size_t)(n0 + srow + 16) * K + scol];
  const int lo0 = (wid * 32) * 32, lo1 = (wid * 32 + 16) * 32;

  for (int kt = 0; kt < K; kt += 64) {
    __syncthreads();
    async16(pa0 + kt, &As0[lo0]);
    async16(pa1 + kt, &As0[lo1]);
    async16(pb0 + kt, &Bs0[lo0]);
    async16(pb1 + kt, &Bs0[lo1]);
    async16(pa0 + kt + 32, &As1[lo0]);
    async16(pa1 + kt + 32, &As1[lo1]);
    async16(pb0 + kt + 32, &Bs1[lo0]);
    async16(pb1 + kt + 32, &Bs1[lo1]);
    __syncthreads();
    {
      bf16x8 af[4], bfr[4];
#pragma unroll
      for (int i = 0; i < 4; ++i)
        af[i] = *(const bf16x8*)&As0[(wm * 64 + i * 16 + l15) * 32 + ((g4 ^ fsw) * 8)];
#pragma unroll
      for (int i = 0; i < 4; ++i)
        bfr[i] = *(const bf16x8*)&Bs0[(wn * 64 + i * 16 + l15) * 32 + ((g4 ^ fsw) * 8)];
#pragma unroll
      for (int mi = 0; mi < 4; ++mi)
#pragma unroll
        for (int ni = 0; ni < 4; ++ni)
          acc[mi][ni] = __builtin_amdgcn_mfma_f32_16x16x32_bf16(af[mi], bfr[ni], acc[mi][ni], 0, 0, 0);
    }
    {
      bf16x8 af[4], bfr[4];
#pragma unroll
      for (int i = 0; i < 4; ++i)
        af[i] = *(const bf16x8*)&As1[(wm * 64 + i * 16 + l15) * 32 + ((g4 ^ fsw) * 8)];
#pragma unroll
      for (int i = 0; i < 4; ++i)
        bfr[i] = *(const bf16x8*)&Bs1[(wn * 64 + i * 16 + l15) * 32 + ((g4 ^ fsw) * 8)];
#pragma unroll
      for (int mi = 0; mi < 4; ++mi)
#pragma unroll
        for (int ni = 0; ni < 4; ++ni)
          acc[mi][ni] = __builtin_amdgcn_mfma_f32_16x16x32_bf16(af[mi], bfr[ni], acc[mi][ni], 0, 0, 0);
    }
  }

  // C/D layout (m89): col = lane&15, row = (lane>>4)*4 + reg
  if (WVT && n0 >= QKW) {
#pragma unroll
    for (int mi = 0; mi < 4; ++mi)
#pragma unroll
      for (int ni = 0; ni < 4; ++ni) {
        const int nv = n0 - QKW + wn * 64 + ni * 16 + l15;
        const int hh = nv >> 7, dd = nv & 127;
        u16* base = &VTout[((size_t)hh * HD + dd) * SEQ];
        const int mb = m0 + wm * 64 + mi * 16 + g4 * 4;
        u16 pk[4];
#pragma unroll
        for (int r = 0; r < 4; ++r) pk[r] = f2bf(acc[mi][ni][r]);
        *(uint2*)&base[mb] = *(uint2*)pk;
      }
  } else {
#pragma unroll
    for (int mi = 0; mi < 4; ++mi)
#pragma unroll
      for (int ni = 0; ni < 4; ++ni) {
        const int n = n0 + wn * 64 + ni * 16 + l15;
#pragma unroll
        for (int r = 0; r < 4; ++r) {
          const int m = m0 + wm * 64 + mi * 16 + g4 * 4 + r;
          float v = acc[mi][ni][r];
          if constexpr (sizeof(OutT) == 2) {
            C[(size_t)m * ldc + n] = (OutT)f2bf(v);
          } else {
            C[(size_t)m * ldc + n] = v;
          }
        }
      }
  }
}

// ---------------- fused attention dispatch ----------------
// R9: T14 reg-staging for the local path (issue-early / write-late).
// R8 (K/V direct from global) regressed: 4x redundant fetch + exposed L2
// latency. R6 (gload_lds prefetch) regressed: same-object LDS aliasing forces
// conservative vmcnt drains + occupancy loss. T14 avoids both: K/V loaded
// global->VGPR (uint4 x8/thread) right after the LDS buffers become visible;
// the HBM latency hides under the FULL compute phase (QK+softmax+PV); the
// ds_writes happen next step between two cheap lgkm-only barriers (vmcnt
// already satisfied by the reg data dependency). ds_reads never alias the
// in-flight loads (registers!) -> no legalizer drains. LDS stays 48KB ->
// 3 blocks/CU preserved; launch_bounds(256,3) caps VGPR at 168 (est ~140).
// Write-side swizzle = same XOR mapping the reads already expect:
//   K: Ks[r*128 + ((c ^ (r&15))*8)], c in [0,16)  (reads use ^l15)
//   V: VTs[d*64 + ((c ^ (d&7))*8)],  c in [0,8)   (reads use ^l7)
// Softmax keeps R7's interior-skip + exp2-domain + T13 defer-max.
__global__ __launch_bounds__(256, 3) void attn_fused(const u16* __restrict__ qk,
                                                     const u16* __restrict__ vt,
                                                     u16* __restrict__ out,
                                                     float* __restrict__ Opart,
                                                     float* __restrict__ MLpart,
                                                     unsigned* __restrict__ cnt) {
  __shared__ __align__(16) u16 smem[24576];   // 48 KB, overlaid per path
  __shared__ unsigned lastflag;
  const int h = blockIdx.y;
  const int tid = threadIdx.x;
  const int lane = tid & 63;

  if (blockIdx.x < 32) {
    // ---------------- local path ----------------
    u16* Ks  = smem;            // [64 kv][128 d] swizzled, 16 KB
    u16* VTs = smem + 8192;     // [128 d][64 kv] swizzled, 16 KB
    u16* Ps  = smem + 16384;    // [128 q][64 kv] swizzled, wave-private rows, 16 KB
    const int q0 = blockIdx.x * 128;
    const int w = tid >> 6;
    const int l15 = lane & 15, g4 = lane >> 4, l7 = lane & 7;

    bf16x8 qf[2][4];
#pragma unroll
    for (int qs = 0; qs < 2; ++qs) {
      const u16* qrow = &qk[(size_t)(q0 + w * 32 + qs * 16 + l15) * QKW + h * HD + g4 * 8];
#pragma unroll
      for (int kk = 0; kk < 4; ++kk) qf[qs][kk] = *(const bf16x8*)&qrow[kk * 32];
    }

    float m_run[2] = {-1e30f, -1e30f}, l_run[2] = {0.f, 0.f};
    f32x4 o[2][8] = {};

    int lo = q0 - 255;
    int lo_blk = (lo < 0) ? 0 : (lo >> 6);
    int hi_blk = (q0 + 382) >> 6;
    if (hi_blk > 63) hi_blk = 63;
    const int extra = (lo_blk > 0) ? 1 : 0;
    const int nsteps = hi_blk - lo_blk + 1 + extra;

    const u16* Kg = qk + 2048 + h * HD;              // K rows in QK buffer
    const u16* Vg = vt + (size_t)h * (HD * SEQ);     // VT[h][d][s]

    uint4 kreg[4], vreg[4];                          // staged next tile (32 VGPR)
    auto loadKV = [&](int kv0) {
#pragma unroll
      for (int p = 0; p < 4; ++p) {
        int idx = tid + p * 256;                     // [0,1024)
        int r = idx >> 4, c = idx & 15;              // K: row r, 16B slot c
        kreg[p] = *(const uint4*)&Kg[(size_t)(kv0 + r) * QKW + c * 8];
      }
#pragma unroll
      for (int p = 0; p < 4; ++p) {
        int idx = tid + p * 256;
        int d = idx >> 3, c = idx & 7;               // V: row d, 16B slot c
        vreg[p] = *(const uint4*)&Vg[(size_t)d * SEQ + kv0 + c * 8];
      }
    };
    auto writeKV = [&]() {
#pragma unroll
      for (int p = 0; p < 4; ++p) {
        int idx = tid + p * 256;
        int r = idx >> 4, c = idx & 15;
        *(uint4*)&Ks[r * 128 + ((c ^ (r & 15)) * 8)] = kreg[p];
      }
#pragma unroll
      for (int p = 0; p < 4; ++p) {
        int idx = tid + p * 256;
        int d = idx >> 3, c = idx & 7;
        *(uint4*)&VTs[d * 64 + ((c ^ (d & 7)) * 8)] = vreg[p];
      }
    };
    auto kb_of = [&](int s) { return (extra && s == 0) ? 0 : (lo_blk + s - extra); };

    loadKV(kb_of(0) * 64);                           // prologue: step-0 into regs

    for (int step = 0; step < nsteps; ++step) {
      const int kv0 = kb_of(step) * 64;
      __syncthreads();          // WAR: all waves done reading previous tiles
      writeKV();                // compiler inserts vmcnt wait for kreg/vreg
      __syncthreads();          // RAW: writes visible to all waves
      if (step + 1 < nsteps) loadKV(kb_of(step + 1) * 64);   // issue early

      f32x4 st[2][4] = {};
#pragma unroll
      for (int kk = 0; kk < 4; ++kk) {
        bf16x8 ak[4];
#pragma unroll
        for (int t4 = 0; t4 < 4; ++t4)
          ak[t4] = *(const bf16x8*)&Ks[(t4 * 16 + l15) * 128 + (((kk * 4 + g4) ^ l15) * 8)];
#pragma unroll
        for (int qs = 0; qs < 2; ++qs)
#pragma unroll
          for (int t4 = 0; t4 < 4; ++t4)
            st[qs][t4] = __builtin_amdgcn_mfma_f32_16x16x32_bf16(ak[t4], qf[qs][kk], st[qs][t4], 0, 0, 0);
      }

#pragma unroll
      for (int qs = 0; qs < 2; ++qs) {
        const int qlo = q0 + w * 32 + qs * 16;
        const int q = qlo + l15;
        float cmax = -1e30f;
        const bool interior = (qlo + 15 - kv0 <= 255) && (kv0 + 63 - qlo <= 255);
        if (interior) {
#pragma unroll
          for (int t4 = 0; t4 < 4; ++t4)
#pragma unroll
            for (int r = 0; r < 4; ++r) {
              float s = st[qs][t4][r] * SC2;
              st[qs][t4][r] = s;
              cmax = fmaxf(cmax, s);
            }
        } else {
#pragma unroll
          for (int t4 = 0; t4 < 4; ++t4)
#pragma unroll
            for (int r = 0; r < 4; ++r) {
              int kv = kv0 + t4 * 16 + g4 * 4 + r;
              int dq = q - kv; if (dq < 0) dq = -dq;
              bool ok = (dq < 256) || (kv < 16);
              float s = ok ? st[qs][t4][r] * SC2 : -1e30f;
              st[qs][t4][r] = s;
              cmax = fmaxf(cmax, s);
            }
        }
        cmax = fmaxf(cmax, __shfl_xor(cmax, 16, 64));
        cmax = fmaxf(cmax, __shfl_xor(cmax, 32, 64));
        const bool defer = __all(cmax <= m_run[qs] + THR2);
        const float mnew = defer ? m_run[qs] : fmaxf(m_run[qs], cmax);
        float csum = 0.f;
#pragma unroll
        for (int t4 = 0; t4 < 4; ++t4)
#pragma unroll
          for (int r = 0; r < 4; ++r) {
            float p = exp2f(st[qs][t4][r] - mnew);
            st[qs][t4][r] = p;
            csum += p;
          }
        csum += __shfl_xor(csum, 16, 64);
        csum += __shfl_xor(csum, 32, 64);

#pragma unroll
        for (int t4 = 0; t4 < 4; ++t4) {
          u16 pk[4];
#pragma unroll
          for (int r = 0; r < 4; ++r) pk[r] = f2bf(st[qs][t4][r]);
          int c8 = t4 * 2 + (g4 >> 1);
          *(uint2*)&Ps[(w * 32 + qs * 16 + l15) * 64 + ((c8 ^ l7) * 8) + (g4 & 1) * 4] = *(uint2*)pk;
        }
        if (defer) {
          l_run[qs] += csum;
        } else {
          float a = exp2f(m_run[qs] - mnew);
          m_run[qs] = mnew;
          l_run[qs] = l_run[qs] * a + csum;
#pragma unroll
          for (int nt = 0; nt < 8; ++nt)
#pragma unroll
            for (int r = 0; r < 4; ++r) o[qs][nt][r] *= a;
        }
      }

#pragma unroll
      for (int ks = 0; ks < 2; ++ks) {
        bf16x8 ap[2];
#pragma unroll
        for (int qs = 0; qs < 2; ++qs)
          ap[qs] = *(const bf16x8*)&Ps[(w * 32 + qs * 16 + l15) * 64 + (((ks * 4 + g4) ^ l7) * 8)];
#pragma unroll
        for (int nt = 0; nt < 8; ++nt) {
          bf16x8 bv = *(const bf16x8*)&VTs[(nt * 16 + l15) * 64 + (((ks * 4 + g4) ^ l7) * 8)];
#pragma unroll
          for (int qs = 0; qs < 2; ++qs)
            o[qs][nt] = __builtin_amdgcn_mfma_f32_16x16x32_bf16(bv, ap[qs], o[qs][nt], 0, 0, 0);
        }
      }
    }

#pragma unroll
    for (int qs = 0; qs < 2; ++qs) {
      if (q0 + w * 32 + qs * 16 < 16) continue;   // rows 0-15 written by global path
      const int q = q0 + w * 32 + qs * 16 + l15;
      const float inv = 1.f / l_run[qs];
#pragma unroll
      for (int nt = 0; nt < 8; ++nt) {
        u16 pk[4];
#pragma unroll
        for (int r = 0; r < 4; ++r) pk[r] = f2bf(o[qs][nt][r] * inv);
        *(uint2*)&out[(size_t)q * HID + h * HD + nt * 16 + g4 * 4] = *(uint2*)pk;
      }
    }
    return;
  }

  // ---------------- global-query path (split-KV) ----------------
  {
    u16* Ks = smem;             // [64][136]
    u16* Vs = smem + 8704;      // [64][136]
    const int chunk = blockIdx.x - 32;
    const int t = tid;
    const int q = t >> 4, dg = t & 15;

    float qr[8];
    {
      bf16x8 v = *(const bf16x8*)&qk[(size_t)q * QKW + h * HD + dg * 8];
#pragma unroll
      for (int j = 0; j < 8; ++j) qr[j] = bf2f((u16)v[j]);
    }
    float m_run = -1e30f, l_run = 0.f, o[8] = {};
    const int kvbase = chunk * (SEQ / GQC);

    for (int st = 0; st < (SEQ / GQC) / 64; ++st) {
      const int kv0 = kvbase + st * 64;
      __syncthreads();
#pragma unroll
      for (int p = 0; p < 4; ++p) {
        int f = (t + p * 256) * 8;
        int r = f >> 7, c = f & 127;
        *(uint4*)&Ks[r * 136 + c] = *(const uint4*)&qk[(size_t)(kv0 + r) * QKW + 2048 + h * HD + c];
      }
#pragma unroll
      for (int p = 0; p < 4; ++p) {
        int id = p * 256 + t;
        int d = id >> 3, c8 = id & 7;
        uint4 v = *(const uint4*)&vt[(size_t)h * (HD * SEQ) + (size_t)d * SEQ + kv0 + c8 * 8];
        const u16* pv16 = (const u16*)&v;
#pragma unroll
        for (int j = 0; j < 8; ++j) Vs[(c8 * 8 + j) * 136 + d] = pv16[j];
      }
      __syncthreads();
      for (int kv = 0; kv < 64; ++kv) {
        bf16x8 kr = *(const bf16x8*)&Ks[kv * 136 + dg * 8];
        float s = 0.f;
#pragma unroll
        for (int j = 0; j < 8; ++j) s += qr[j] * bf2f((u16)kr[j]);
        s += __shfl_xor(s, 1, 64); s += __shfl_xor(s, 2, 64);
        s += __shfl_xor(s, 4, 64); s += __shfl_xor(s, 8, 64);
        s *= SCALE;
        float mnew = fmaxf(m_run, s);
        float alpha = __expf(m_run - mnew);
        float p = __expf(s - mnew);
        m_run = mnew;
        l_run = l_run * alpha + p;
        bf16x8 vr = *(const bf16x8*)&Vs[kv * 136 + dg * 8];
#pragma unroll
        for (int j = 0; j < 8; ++j) o[j] = o[j] * alpha + p * bf2f((u16)vr[j]);
      }
    }
    float* op = &Opart[(((size_t)h * GQC + chunk) * 16 + q) * HD + dg * 8];
#pragma unroll
    for (int j = 0; j < 8; ++j) op[j] = o[j];
    if (dg == 0) {
      float* ml = &MLpart[(((size_t)h * GQC + chunk) * 16 + q) * 2];
      ml[0] = m_run; ml[1] = l_run;
    }

    // last-chunk-done reduction for this head
    __syncthreads();                 // all waves' stores drained (vmcnt 0 before barrier)
    if (t == 0) {
      __threadfence();               // release: flush XCD L2 to coherence point
      lastflag = (atomicAdd(&cnt[h], 1u) == GQC - 1) ? 1u : 0u;
    }
    __syncthreads();
    if (lastflag) {
      __threadfence();               // acquire: invalidate stale cached partials
      float M = -1e30f;
      for (int c = 0; c < GQC; ++c)
        M = fmaxf(M, MLpart[(((size_t)h * GQC + c) * 16 + q) * 2]);
      float L = 0.f, oo[8] = {};
      for (int c = 0; c < GQC; ++c) {
        const float* ml = &MLpart[(((size_t)h * GQC + c) * 16 + q) * 2];
        float e = __expf(ml[0] - M);
        L += e * ml[1];
        const float* opc = &Opart[(((size_t)h * GQC + c) * 16 + q) * HD + dg * 8];
#pragma unroll
        for (int j = 0; j < 8; ++j) oo[j] += e * opc[j];
      }
      float inv = 1.f / L;
      u16 tmp[8];
#pragma unroll
      for (int j = 0; j < 8; ++j) tmp[j] = f2bf(oo[j] * inv);
      *(uint4*)&out[(size_t)q * HID + h * HD + dg * 8] = *(uint4*)tmp;
    }
  }
}

extern "C" void kernel_launch(void* const* d_in, const int* in_sizes, int n_in,
                              void* d_out, int out_size, void* d_ws, size_t ws_size,
                              hipStream_t stream) {
  const float* X  = (const float*)d_in[0];
  const float* Wq = (const float*)d_in[1];
  const float* Wk = (const float*)d_in[2];
  const float* Wv = (const float*)d_in[3];
  const float* Wo = (const float*)d_in[4];
  float* out = (float*)d_out;

  // workspace layout (96 MiB, lifetime-aliased):
  //  [0,16M):   Xbf   (dead after QKV GEMM)
  //  [16M,40M): Wcat  (dead after QKV GEMM) -> [16M,32M) AttnO, [32M,36M) Opart,
  //                                            [36M,36M+64K) MLpart
  //  [40M,72M): QK row-major [4096][4096] bf16 (Q | K)
  //  [72M,88M): VT[h][d][s] bf16 (written directly by QKV GEMM epilogue)
  //  [88M,96M): Wo^T bf16
  //  cnt -> first 64 B of d_out (untouched until final GEMM overwrites it).
  char* ws = (char*)d_ws;
  u16* Xbf    = (u16*)(ws);
  u16* Wcat   = (u16*)(ws + (size_t)(16 << 20));
  u16* AttnO  = (u16*)(ws + (size_t)(16 << 20));     // alias Wcat (post-GEMM)
  float* Opart  = (float*)(ws + (size_t)(32 << 20));
  float* MLpart = (float*)(ws + (size_t)(36 << 20));
  unsigned* cnt = (unsigned*)d_out;
  u16* QK     = (u16*)(ws + (size_t)(40 << 20));
  u16* VT     = (u16*)(ws + (size_t)(72 << 20));
  u16* Wot    = (u16*)(ws + (size_t)(88 << 20));

  // 1) prep: X->bf16, weight transposes, counter zero (one dispatch)
  prep<<<dim3(12288), 256, 0, stream>>>(X, Wq, Wk, Wv, Wo, Xbf, Wcat, Wot, cnt);
  // 2) fused QKV GEMM (128^2 m97 + slot swizzle): Q,K -> QK; V -> VT
  gemm_bt<u16, true><<<dim3(48, 32), 256, 0, stream>>>(Xbf, Wcat, QK, VT, HID, QKW);
  // 3) fused attention (R9: T14 reg-staged K/V, latency hidden under compute)
  attn_fused<<<dim3(32 + GQC, NH), 256, 0, stream>>>(QK, VT, AttnO, Opart, MLpart, cnt);
  // 4) output projection -> fp32 out (overwrites cnt bytes with real output)
  gemm_bt<float, false><<<dim3(16, 32), 256, 0, stream>>>(AttnO, Wot, out, nullptr, HID, HID);
}

// Round 10
// 411.251 us; speedup vs baseline: 1.2591x; 1.2591x over previous
//
#include <hip/hip_runtime.h>
#include <stdint.h>

#define SEQ    4096
#define HID    2048
#define NQKV   6144
#define QKW    4096   // width of the QK row-major buffer (Q | K)
#define NH     16
#define HD     128
#define SCALE  0.08838834764831845f
#define SC2    0.1275174400460405f   // SCALE * log2(e): softmax in exp2 domain
#define THR2   11.5f                 // defer-max threshold (~e^8 in log2 units)
#define GQC    32     // split-KV chunks for global-query path (128 kv each)

typedef unsigned short u16;
typedef __attribute__((ext_vector_type(8))) short bf16x8;
typedef __attribute__((ext_vector_type(4))) float f32x4;

__device__ __forceinline__ u16 f2bf(float f) {
  union { float f; unsigned u; } v; v.f = f;
  unsigned r = v.u + 0x7FFFu + ((v.u >> 16) & 1u);
  return (u16)(r >> 16);
}

__device__ __forceinline__ float bf2f(u16 b) {
  union { unsigned u; float f; } c; c.u = ((unsigned)b) << 16; return c.f;
}

__device__ __forceinline__ void async16(const u16* g, u16* l) {
  __builtin_amdgcn_global_load_lds(
      (const __attribute__((address_space(1))) unsigned int*)g,
      (__attribute__((address_space(3))) unsigned int*)l, 16, 0, 0);
}

// ---------------- prep: X->bf16 convert + 4 weight transposes + counter zero ----------------
__global__ __launch_bounds__(256) void prep(const float* __restrict__ X,
                                            const float* __restrict__ W0,
                                            const float* __restrict__ W1,
                                            const float* __restrict__ W2,
                                            const float* __restrict__ W3,
                                            u16* __restrict__ Xbf,
                                            u16* __restrict__ Wcat,
                                            u16* __restrict__ Wot,
                                            unsigned* __restrict__ cnt) {
  const int bx = blockIdx.x;
  const int t = threadIdx.x;
  if (bx == 0 && t < NH) cnt[t] = 0u;     // zero split-K completion counters
  if (bx < 8192) {
    int i = bx * 256 + t;
    float4 v = ((const float4*)X)[i];
    ushort4 o;
    o.x = f2bf(v.x); o.y = f2bf(v.y); o.z = f2bf(v.z); o.w = f2bf(v.w);
    ((ushort4*)Xbf)[i] = o;
    return;
  }
  __shared__ __align__(16) u16 Ts[64 * 68];
  const int b = bx - 8192;
  const int z = b >> 10;
  const int k0 = ((b >> 5) & 31) * 64;
  const int n0 = (b & 31) * 64;
  const float* W = (z == 0) ? W0 : (z == 1) ? W1 : (z == 2) ? W2 : W3;
  u16* Wt = (z < 3) ? (Wcat + (size_t)z * 2048 * 2048) : Wot;
#pragma unroll
  for (int p = 0; p < 4; ++p) {
    int f = (t + p * 256) * 4;
    int r = f >> 6, c = f & 63;            // r=k_local, c=n_local
    float4 v = *(const float4*)&W[(size_t)(k0 + r) * 2048 + n0 + c];
    ushort4 o; o.x = f2bf(v.x); o.y = f2bf(v.y); o.z = f2bf(v.z); o.w = f2bf(v.w);
    *(ushort4*)&Ts[r * 68 + c] = o;
  }
  __syncthreads();
#pragma unroll
  for (int p = 0; p < 4; ++p) {
    int g = (t + p * 256) * 4;
    int r = g >> 6, c = g & 63;            // r=n_local, c=k_local
    ushort4 o;
    o.x = Ts[(c + 0) * 68 + r];
    o.y = Ts[(c + 1) * 68 + r];
    o.z = Ts[(c + 2) * 68 + r];
    o.w = Ts[(c + 3) * 68 + r];
    *(ushort4*)&Wt[(size_t)(n0 + r) * 2048 + k0 + c] = o;
  }
}

// ---------------- 128x128 GEMM, m97 structure + LDS slot-swizzle (frozen) ----------------
// R5 verified: swizzle -> SQ_LDS_BANK_CONFLICT 1.26e7 -> 0; at the m97
// structural ceiling (MfmaUtil 37%, 15% HBM); 8-phase escape nulled 3x
// (R2/R3/R4, matching the guide's OPEN 128^2+8ph quadrant).
template <typename OutT, bool WVT>
__global__ __launch_bounds__(256) void gemm_bt(const u16* __restrict__ A,
                                               const u16* __restrict__ B,
                                               OutT* __restrict__ C,
                                               u16* __restrict__ VTout,
                                               int K, int ldc) {
  __shared__ __align__(16) u16 As0[128 * 32];
  __shared__ __align__(16) u16 As1[128 * 32];
  __shared__ __align__(16) u16 Bs0[128 * 32];
  __shared__ __align__(16) u16 Bs1[128 * 32];
  const int m0 = blockIdx.y * 128;
  const int n0 = blockIdx.x * 128;
  const int tid = threadIdx.x;
  const int wid = tid >> 6;
  const int lane = tid & 63;
  const int wm = wid & 1, wn = wid >> 1;
  const int l15 = lane & 15, g4 = lane >> 4;

  const int srow = wid * 32 + (lane >> 2);
  const int scol = ((lane & 3) ^ ((lane >> 3) & 3)) * 8;
  const int fsw = (l15 >> 1) & 3;

  f32x4 acc[4][4] = {};

  const u16* pa0 = &A[(size_t)(m0 + srow) * K + scol];
  const u16* pa1 = &A[(size_t)(m0 + srow + 16) * K + scol];
  const u16* pb0 = &B[(size_t)(n0 + srow) * K + scol];
  const u16* pb1 = &B[(size_t)(n0 + srow + 16) * K + scol];
  const int lo0 = (wid * 32) * 32, lo1 = (wid * 32 + 16) * 32;

  for (int kt = 0; kt < K; kt += 64) {
    __syncthreads();
    async16(pa0 + kt, &As0[lo0]);
    async16(pa1 + kt, &As0[lo1]);
    async16(pb0 + kt, &Bs0[lo0]);
    async16(pb1 + kt, &Bs0[lo1]);
    async16(pa0 + kt + 32, &As1[lo0]);
    async16(pa1 + kt + 32, &As1[lo1]);
    async16(pb0 + kt + 32, &Bs1[lo0]);
    async16(pb1 + kt + 32, &Bs1[lo1]);
    __syncthreads();
    {
      bf16x8 af[4], bfr[4];
#pragma unroll
      for (int i = 0; i < 4; ++i)
        af[i] = *(const bf16x8*)&As0[(wm * 64 + i * 16 + l15) * 32 + ((g4 ^ fsw) * 8)];
#pragma unroll
      for (int i = 0; i < 4; ++i)
        bfr[i] = *(const bf16x8*)&Bs0[(wn * 64 + i * 16 + l15) * 32 + ((g4 ^ fsw) * 8)];
#pragma unroll
      for (int mi = 0; mi < 4; ++mi)
#pragma unroll
        for (int ni = 0; ni < 4; ++ni)
          acc[mi][ni] = __builtin_amdgcn_mfma_f32_16x16x32_bf16(af[mi], bfr[ni], acc[mi][ni], 0, 0, 0);
    }
    {
      bf16x8 af[4], bfr[4];
#pragma unroll
      for (int i = 0; i < 4; ++i)
        af[i] = *(const bf16x8*)&As1[(wm * 64 + i * 16 + l15) * 32 + ((g4 ^ fsw) * 8)];
#pragma unroll
      for (int i = 0; i < 4; ++i)
        bfr[i] = *(const bf16x8*)&Bs1[(wn * 64 + i * 16 + l15) * 32 + ((g4 ^ fsw) * 8)];
#pragma unroll
      for (int mi = 0; mi < 4; ++mi)
#pragma unroll
        for (int ni = 0; ni < 4; ++ni)
          acc[mi][ni] = __builtin_amdgcn_mfma_f32_16x16x32_bf16(af[mi], bfr[ni], acc[mi][ni], 0, 0, 0);
    }
  }

  // C/D layout (m89): col = lane&15, row = (lane>>4)*4 + reg
  if (WVT && n0 >= QKW) {
#pragma unroll
    for (int mi = 0; mi < 4; ++mi)
#pragma unroll
      for (int ni = 0; ni < 4; ++ni) {
        const int nv = n0 - QKW + wn * 64 + ni * 16 + l15;
        const int hh = nv >> 7, dd = nv & 127;
        u16* base = &VTout[((size_t)hh * HD + dd) * SEQ];
        const int mb = m0 + wm * 64 + mi * 16 + g4 * 4;
        u16 pk[4];
#pragma unroll
        for (int r = 0; r < 4; ++r) pk[r] = f2bf(acc[mi][ni][r]);
        *(uint2*)&base[mb] = *(uint2*)pk;
      }
  } else {
#pragma unroll
    for (int mi = 0; mi < 4; ++mi)
#pragma unroll
      for (int ni = 0; ni < 4; ++ni) {
        const int n = n0 + wn * 64 + ni * 16 + l15;
#pragma unroll
        for (int r = 0; r < 4; ++r) {
          const int m = m0 + wm * 64 + mi * 16 + g4 * 4 + r;
          float v = acc[mi][ni][r];
          if constexpr (sizeof(OutT) == 2) {
            C[(size_t)m * ldc + n] = (OutT)f2bf(v);
          } else {
            C[(size_t)m * ldc + n] = v;
          }
        }
      }
  }
}

// ---------------- fused attention dispatch ----------------
// R10: reverted to the R7 structure — the session's verified local optimum.
// Pipelining post-mortems (each a distinct failure mechanism):
//   R6 LDS dbuf   -> 80KB = 1 blk/CU, occupancy loss        (174 us)
//   R8 no staging -> 4x redundant fetch + exposed L2 latency (192 us)
//   R9 reg-stage  -> launch_bounds(256,3) demoted the staged arrays to
//                    scratch (VGPR 84, WRITE_SIZE 21->219MB) (234 us)
// Synchronous 48KB staging at 3 blks/CU (12-wave TLP) beats every
// pipelined variant on this problem. Softmax keeps R7's validated cuts:
// interior-mask skip, exp2-domain, T13 defer-max.
__global__ __launch_bounds__(256, 2) void attn_fused(const u16* __restrict__ qk,
                                                     const u16* __restrict__ vt,
                                                     u16* __restrict__ out,
                                                     float* __restrict__ Opart,
                                                     float* __restrict__ MLpart,
                                                     unsigned* __restrict__ cnt) {
  __shared__ __align__(16) u16 smem[24576];   // 48 KB, overlaid per path
  __shared__ unsigned lastflag;
  const int h = blockIdx.y;
  const int tid = threadIdx.x;
  const int lane = tid & 63;

  if (blockIdx.x < 32) {
    // ---------------- local path ----------------
    u16* Ks  = smem;            // [64 kv][128 d] swizzled, 16 KB
    u16* VTs = smem + 8192;     // [128 d][64 kv] swizzled, 16 KB
    u16* Ps  = smem + 16384;    // [128 q][64 kv] swizzled, wave-private rows, 16 KB
    const int q0 = blockIdx.x * 128;
    const int w = tid >> 6;
    const int l15 = lane & 15, g4 = lane >> 4, l7 = lane & 7;

    bf16x8 qf[2][4];
#pragma unroll
    for (int qs = 0; qs < 2; ++qs) {
      const u16* qrow = &qk[(size_t)(q0 + w * 32 + qs * 16 + l15) * QKW + h * HD + g4 * 8];
#pragma unroll
      for (int kk = 0; kk < 4; ++kk) qf[qs][kk] = *(const bf16x8*)&qrow[kk * 32];
    }

    float m_run[2] = {-1e30f, -1e30f}, l_run[2] = {0.f, 0.f};
    f32x4 o[2][8] = {};

    int lo = q0 - 255;
    int lo_blk = (lo < 0) ? 0 : (lo >> 6);
    int hi_blk = (q0 + 382) >> 6;
    if (hi_blk > 63) hi_blk = 63;
    const int extra = (lo_blk > 0) ? 1 : 0;
    const int nsteps = hi_blk - lo_blk + 1 + extra;

    for (int step = 0; step < nsteps; ++step) {
      const int kb = (extra && step == 0) ? 0 : (lo_blk + step - extra);
      const int kv0 = kb * 64;
      __syncthreads();
#pragma unroll
      for (int p = 0; p < 4; ++p) {
        const int r = w * 16 + p * 4 + (lane >> 4);
        const u16* src = &qk[(size_t)(kv0 + r) * QKW + 2048 + h * HD + (((lane & 15) ^ (r & 15)) * 8)];
        async16(src, &Ks[(w * 16 + p * 4) * 128]);
      }
#pragma unroll
      for (int p = 0; p < 4; ++p) {
        const int r = w * 32 + p * 8 + (lane >> 3);
        const u16* src = &vt[(size_t)h * (HD * SEQ) + (size_t)r * SEQ + kv0 + (((lane & 7) ^ (r & 7)) * 8)];
        async16(src, &VTs[(w * 32 + p * 8) * 64]);
      }
      __syncthreads();

      f32x4 st[2][4] = {};
#pragma unroll
      for (int kk = 0; kk < 4; ++kk) {
        bf16x8 ak[4];
#pragma unroll
        for (int t4 = 0; t4 < 4; ++t4)
          ak[t4] = *(const bf16x8*)&Ks[(t4 * 16 + l15) * 128 + (((kk * 4 + g4) ^ l15) * 8)];
#pragma unroll
        for (int qs = 0; qs < 2; ++qs)
#pragma unroll
          for (int t4 = 0; t4 < 4; ++t4)
            st[qs][t4] = __builtin_amdgcn_mfma_f32_16x16x32_bf16(ak[t4], qf[qs][kk], st[qs][t4], 0, 0, 0);
      }

#pragma unroll
      for (int qs = 0; qs < 2; ++qs) {
        const int qlo = q0 + w * 32 + qs * 16;
        const int q = qlo + l15;
        float cmax = -1e30f;
        const bool interior = (qlo + 15 - kv0 <= 255) && (kv0 + 63 - qlo <= 255);
        if (interior) {
#pragma unroll
          for (int t4 = 0; t4 < 4; ++t4)
#pragma unroll
            for (int r = 0; r < 4; ++r) {
              float s = st[qs][t4][r] * SC2;
              st[qs][t4][r] = s;
              cmax = fmaxf(cmax, s);
            }
        } else {
#pragma unroll
          for (int t4 = 0; t4 < 4; ++t4)
#pragma unroll
            for (int r = 0; r < 4; ++r) {
              int kv = kv0 + t4 * 16 + g4 * 4 + r;
              int dq = q - kv; if (dq < 0) dq = -dq;
              bool ok = (dq < 256) || (kv < 16);
              float s = ok ? st[qs][t4][r] * SC2 : -1e30f;
              st[qs][t4][r] = s;
              cmax = fmaxf(cmax, s);
            }
        }
        cmax = fmaxf(cmax, __shfl_xor(cmax, 16, 64));
        cmax = fmaxf(cmax, __shfl_xor(cmax, 32, 64));
        const bool defer = __all(cmax <= m_run[qs] + THR2);
        const float mnew = defer ? m_run[qs] : fmaxf(m_run[qs], cmax);
        float csum = 0.f;
#pragma unroll
        for (int t4 = 0; t4 < 4; ++t4)
#pragma unroll
          for (int r = 0; r < 4; ++r) {
            float p = exp2f(st[qs][t4][r] - mnew);
            st[qs][t4][r] = p;
            csum += p;
          }
        csum += __shfl_xor(csum, 16, 64);
        csum += __shfl_xor(csum, 32, 64);

#pragma unroll
        for (int t4 = 0; t4 < 4; ++t4) {
          u16 pk[4];
#pragma unroll
          for (int r = 0; r < 4; ++r) pk[r] = f2bf(st[qs][t4][r]);
          int c8 = t4 * 2 + (g4 >> 1);
          *(uint2*)&Ps[(w * 32 + qs * 16 + l15) * 64 + ((c8 ^ l7) * 8) + (g4 & 1) * 4] = *(uint2*)pk;
        }
        if (defer) {
          l_run[qs] += csum;
        } else {
          float a = exp2f(m_run[qs] - mnew);
          m_run[qs] = mnew;
          l_run[qs] = l_run[qs] * a + csum;
#pragma unroll
          for (int nt = 0; nt < 8; ++nt)
#pragma unroll
            for (int r = 0; r < 4; ++r) o[qs][nt][r] *= a;
        }
      }

#pragma unroll
      for (int ks = 0; ks < 2; ++ks) {
        bf16x8 ap[2];
#pragma unroll
        for (int qs = 0; qs < 2; ++qs)
          ap[qs] = *(const bf16x8*)&Ps[(w * 32 + qs * 16 + l15) * 64 + (((ks * 4 + g4) ^ l7) * 8)];
#pragma unroll
        for (int nt = 0; nt < 8; ++nt) {
          bf16x8 bv = *(const bf16x8*)&VTs[(nt * 16 + l15) * 64 + (((ks * 4 + g4) ^ l7) * 8)];
#pragma unroll
          for (int qs = 0; qs < 2; ++qs)
            o[qs][nt] = __builtin_amdgcn_mfma_f32_16x16x32_bf16(bv, ap[qs], o[qs][nt], 0, 0, 0);
        }
      }
    }

#pragma unroll
    for (int qs = 0; qs < 2; ++qs) {
      if (q0 + w * 32 + qs * 16 < 16) continue;   // rows 0-15 written by global path
      const int q = q0 + w * 32 + qs * 16 + l15;
      const float inv = 1.f / l_run[qs];
#pragma unroll
      for (int nt = 0; nt < 8; ++nt) {
        u16 pk[4];
#pragma unroll
        for (int r = 0; r < 4; ++r) pk[r] = f2bf(o[qs][nt][r] * inv);
        *(uint2*)&out[(size_t)q * HID + h * HD + nt * 16 + g4 * 4] = *(uint2*)pk;
      }
    }
    return;
  }

  // ---------------- global-query path (split-KV) ----------------
  {
    u16* Ks = smem;             // [64][136]
    u16* Vs = smem + 8704;      // [64][136]
    const int chunk = blockIdx.x - 32;
    const int t = tid;
    const int q = t >> 4, dg = t & 15;

    float qr[8];
    {
      bf16x8 v = *(const bf16x8*)&qk[(size_t)q * QKW + h * HD + dg * 8];
#pragma unroll
      for (int j = 0; j < 8; ++j) qr[j] = bf2f((u16)v[j]);
    }
    float m_run = -1e30f, l_run = 0.f, o[8] = {};
    const int kvbase = chunk * (SEQ / GQC);

    for (int st = 0; st < (SEQ / GQC) / 64; ++st) {
      const int kv0 = kvbase + st * 64;
      __syncthreads();
#pragma unroll
      for (int p = 0; p < 4; ++p) {
        int f = (t + p * 256) * 8;
        int r = f >> 7, c = f & 127;
        *(uint4*)&Ks[r * 136 + c] = *(const uint4*)&qk[(size_t)(kv0 + r) * QKW + 2048 + h * HD + c];
      }
#pragma unroll
      for (int p = 0; p < 4; ++p) {
        int id = p * 256 + t;
        int d = id >> 3, c8 = id & 7;
        uint4 v = *(const uint4*)&vt[(size_t)h * (HD * SEQ) + (size_t)d * SEQ + kv0 + c8 * 8];
        const u16* pv16 = (const u16*)&v;
#pragma unroll
        for (int j = 0; j < 8; ++j) Vs[(c8 * 8 + j) * 136 + d] = pv16[j];
      }
      __syncthreads();
      for (int kv = 0; kv < 64; ++kv) {
        bf16x8 kr = *(const bf16x8*)&Ks[kv * 136 + dg * 8];
        float s = 0.f;
#pragma unroll
        for (int j = 0; j < 8; ++j) s += qr[j] * bf2f((u16)kr[j]);
        s += __shfl_xor(s, 1, 64); s += __shfl_xor(s, 2, 64);
        s += __shfl_xor(s, 4, 64); s += __shfl_xor(s, 8, 64);
        s *= SCALE;
        float mnew = fmaxf(m_run, s);
        float alpha = __expf(m_run - mnew);
        float p = __expf(s - mnew);
        m_run = mnew;
        l_run = l_run * alpha + p;
        bf16x8 vr = *(const bf16x8*)&Vs[kv * 136 + dg * 8];
#pragma unroll
        for (int j = 0; j < 8; ++j) o[j] = o[j] * alpha + p * bf2f((u16)vr[j]);
      }
    }
    float* op = &Opart[(((size_t)h * GQC + chunk) * 16 + q) * HD + dg * 8];
#pragma unroll
    for (int j = 0; j < 8; ++j) op[j] = o[j];
    if (dg == 0) {
      float* ml = &MLpart[(((size_t)h * GQC + chunk) * 16 + q) * 2];
      ml[0] = m_run; ml[1] = l_run;
    }

    // last-chunk-done reduction for this head
    __syncthreads();                 // all waves' stores drained (vmcnt 0 before barrier)
    if (t == 0) {
      __threadfence();               // release: flush XCD L2 to coherence point
      lastflag = (atomicAdd(&cnt[h], 1u) == GQC - 1) ? 1u : 0u;
    }
    __syncthreads();
    if (lastflag) {
      __threadfence();               // acquire: invalidate stale cached partials
      float M = -1e30f;
      for (int c = 0; c < GQC; ++c)
        M = fmaxf(M, MLpart[(((size_t)h * GQC + c) * 16 + q) * 2]);
      float L = 0.f, oo[8] = {};
      for (int c = 0; c < GQC; ++c) {
        const float* ml = &MLpart[(((size_t)h * GQC + c) * 16 + q) * 2];
        float e = __expf(ml[0] - M);
        L += e * ml[1];
        const float* opc = &Opart[(((size_t)h * GQC + c) * 16 + q) * HD + dg * 8];
#pragma unroll
        for (int j = 0; j < 8; ++j) oo[j] += e * opc[j];
      }
      float inv = 1.f / L;
      u16 tmp[8];
#pragma unroll
      for (int j = 0; j < 8; ++j) tmp[j] = f2bf(oo[j] * inv);
      *(uint4*)&out[(size_t)q * HID + h * HD + dg * 8] = *(uint4*)tmp;
    }
  }
}

extern "C" void kernel_launch(void* const* d_in, const int* in_sizes, int n_in,
                              void* d_out, int out_size, void* d_ws, size_t ws_size,
                              hipStream_t stream) {
  const float* X  = (const float*)d_in[0];
  const float* Wq = (const float*)d_in[1];
  const float* Wk = (const float*)d_in[2];
  const float* Wv = (const float*)d_in[3];
  const float* Wo = (const float*)d_in[4];
  float* out = (float*)d_out;

  // workspace layout (96 MiB, lifetime-aliased):
  //  [0,16M):   Xbf   (dead after QKV GEMM)
  //  [16M,40M): Wcat  (dead after QKV GEMM) -> [16M,32M) AttnO, [32M,36M) Opart,
  //                                            [36M,36M+64K) MLpart
  //  [40M,72M): QK row-major [4096][4096] bf16 (Q | K)
  //  [72M,88M): VT[h][d][s] bf16 (written directly by QKV GEMM epilogue)
  //  [88M,96M): Wo^T bf16
  //  cnt -> first 64 B of d_out (untouched until final GEMM overwrites it).
  char* ws = (char*)d_ws;
  u16* Xbf    = (u16*)(ws);
  u16* Wcat   = (u16*)(ws + (size_t)(16 << 20));
  u16* AttnO  = (u16*)(ws + (size_t)(16 << 20));     // alias Wcat (post-GEMM)
  float* Opart  = (float*)(ws + (size_t)(32 << 20));
  float* MLpart = (float*)(ws + (size_t)(36 << 20));
  unsigned* cnt = (unsigned*)d_out;
  u16* QK     = (u16*)(ws + (size_t)(40 << 20));
  u16* VT     = (u16*)(ws + (size_t)(72 << 20));
  u16* Wot    = (u16*)(ws + (size_t)(88 << 20));

  // 1) prep: X->bf16, weight transposes, counter zero (one dispatch)
  prep<<<dim3(12288), 256, 0, stream>>>(X, Wq, Wk, Wv, Wo, Xbf, Wcat, Wot, cnt);
  // 2) fused QKV GEMM (128^2 m97 + slot swizzle): Q,K -> QK; V -> VT
  gemm_bt<u16, true><<<dim3(48, 32), 256, 0, stream>>>(Xbf, Wcat, QK, VT, HID, QKW);
  // 3) fused attention (R10: reverted to the verified R7 structure)
  attn_fused<<<dim3(32 + GQC, NH), 256, 0, stream>>>(QK, VT, AttnO, Opart, MLpart, cnt);
  // 4) output projection -> fp32 out (overwrites cnt bytes with real output)
  gemm_bt<float, false><<<dim3(16, 32), 256, 0, stream>>>(AttnO, Wot, out, nullptr, HID, HID);
}